// Round 1
// baseline (1014.503 us; speedup 1.0000x reference)
//
#include <hip/hip_runtime.h>
#include <math.h>

#define NN 100000
#define NE 1000000
#define D  64
#define NB_SCAN 391   // ceil(NN/256)

// ================= CSR build (counting sort by dst) =================

__global__ __launch_bounds__(256) void k_hist(
    const int* __restrict__ dst, int* __restrict__ counts, int* __restrict__ rank)
{
    int e = blockIdx.x * 256 + threadIdx.x;
    if (e >= NE) return;
    rank[e] = atomicAdd(&counts[dst[e]], 1);
}

__global__ __launch_bounds__(256) void k_scan1(
    const int* __restrict__ counts, int* __restrict__ row_start, int* __restrict__ bsum)
{
    __shared__ int s[256];
    int t = threadIdx.x;
    int i = blockIdx.x * 256 + t;
    int v = (i < NN) ? counts[i] : 0;
    s[t] = v; __syncthreads();
#pragma unroll
    for (int off = 1; off < 256; off <<= 1) {
        int add = (t >= off) ? s[t - off] : 0;
        __syncthreads();
        s[t] += add;
        __syncthreads();
    }
    if (i < NN) row_start[i] = s[t] - v;       // local exclusive
    if (t == 255) bsum[blockIdx.x] = s[255];   // block total
}

__global__ __launch_bounds__(512) void k_scan2(
    const int* __restrict__ bsum, int* __restrict__ boff, int* __restrict__ row_start)
{
    __shared__ int s[512];
    int t = threadIdx.x;
    int v = (t < NB_SCAN) ? bsum[t] : 0;
    s[t] = v; __syncthreads();
#pragma unroll
    for (int off = 1; off < 512; off <<= 1) {
        int add = (t >= off) ? s[t - off] : 0;
        __syncthreads();
        s[t] += add;
        __syncthreads();
    }
    if (t < NB_SCAN) boff[t] = s[t] - v;       // exclusive block offsets
    if (t == 0) row_start[NN] = NE;
}

__global__ __launch_bounds__(256) void k_scan3(
    int* __restrict__ row_start, const int* __restrict__ boff)
{
    int i = blockIdx.x * 256 + threadIdx.x;
    if (i < NN) row_start[i] += boff[i >> 8];
}

__global__ __launch_bounds__(256) void k_scatter(
    const int* __restrict__ dst, const int* __restrict__ src,
    const int* __restrict__ perm, const int* __restrict__ rank,
    const int* __restrict__ row_start, int4* __restrict__ sorted)
{
    int e = blockIdx.x * 256 + threadIdx.x;
    if (e >= NE) return;
    int pos = row_start[dst[e]] + rank[e];
    sorted[pos] = make_int4(src[e], e, perm[e], 0);   // single 16B line-local write
}

// one-time weight transpose: W[64][128] (torch [out][in]) -> Wt[128][64]
// so the GEMM B-read Wt[k][tx4..tx4+3] is a contiguous 256B wave read.
__global__ __launch_bounds__(256) void k_wt4(
    const float* __restrict__ W0, const float* __restrict__ W1,
    const float* __restrict__ W2, const float* __restrict__ W3,
    float* __restrict__ T0, float* __restrict__ T1,
    float* __restrict__ T2, float* __restrict__ T3)
{
    int t = blockIdx.x * 256 + threadIdx.x;   // 4 * 8192 elements
    int m = t >> 13, idx = t & 8191;
    const float* W = (m == 0) ? W0 : (m == 1) ? W1 : (m == 2) ? W2 : W3;
    float*       T = (m == 0) ? T0 : (m == 1) ? T1 : (m == 2) ? T2 : T3;
    int j = idx >> 7, k = idx & 127;
    T[k * 64 + j] = W[idx];
}

// ================= pull-based segment sums (no atomics) =================
// wave = node; lane = (edge_slot es=lane>>4, chan4 c4=(lane&15)*4); 16B/lane
// gathers. ~5.1 TB/s delivered (R6) — near the random-256B-gather ceiling.

__global__ __launch_bounds__(256) void pull_pass1(
    const int4* __restrict__ sorted, const int* __restrict__ row_start,
    const float* __restrict__ nfeats, const float* __restrict__ efeats,
    float* __restrict__ hsum0, float* __restrict__ efsP, float* __restrict__ efsN)
{
    int gt = blockIdx.x * 256 + threadIdx.x;
    int w = gt >> 6, lane = gt & 63;
    if (w >= NN) return;
    int es = lane >> 4, c4 = (lane & 15) << 2;
    int beg = row_start[w], end = row_start[w + 1];

    float an0 = 0.f, an1 = 0.f, an2 = 0.f, an3 = 0.f;
    float ap0 = 0.f, ap1 = 0.f, ap2 = 0.f, ap3 = 0.f;
    float ag0 = 0.f, ag1 = 0.f, ag2 = 0.f, ag3 = 0.f;
    int i = beg + es;
    int4 q = (i < end) ? sorted[i] : make_int4(0, 0, 0, 0);
#pragma unroll 1
    for (; i < end; i += 4) {
        int inext = i + 4;
        int4 qn = (inext < end) ? sorted[inext] : make_int4(0, 0, 0, 0);
        float4 n  = *(const float4*)(nfeats + (size_t)q.x * D + c4);
        float4 ep = *(const float4*)(efeats + (size_t)q.y * D + c4);
        float4 en = *(const float4*)(efeats + (size_t)q.z * D + c4);
        an0 += n.x;  an1 += n.y;  an2 += n.z;  an3 += n.w;
        ap0 += ep.x; ap1 += ep.y; ap2 += ep.z; ap3 += ep.w;
        ag0 += en.x; ag1 += en.y; ag2 += en.z; ag3 += en.w;
        q = qn;
    }
#pragma unroll
    for (int off = 16; off <= 32; off <<= 1) {
        an0 += __shfl_xor(an0, off, 64); an1 += __shfl_xor(an1, off, 64);
        an2 += __shfl_xor(an2, off, 64); an3 += __shfl_xor(an3, off, 64);
        ap0 += __shfl_xor(ap0, off, 64); ap1 += __shfl_xor(ap1, off, 64);
        ap2 += __shfl_xor(ap2, off, 64); ap3 += __shfl_xor(ap3, off, 64);
        ag0 += __shfl_xor(ag0, off, 64); ag1 += __shfl_xor(ag1, off, 64);
        ag2 += __shfl_xor(ag2, off, 64); ag3 += __shfl_xor(ag3, off, 64);
    }
    if (lane < 16) {
        *(float4*)(hsum0 + (size_t)w * D + c4) = make_float4(an0, an1, an2, an3);
        *(float4*)(efsP  + (size_t)w * D + c4) = make_float4(ap0, ap1, ap2, ap3);
        *(float4*)(efsN  + (size_t)w * D + c4) = make_float4(ag0, ag1, ag2, ag3);
    }
}

__global__ __launch_bounds__(256) void pull_h2(
    const int4* __restrict__ sorted, const int* __restrict__ row_start,
    const float* __restrict__ hP, const float* __restrict__ hN,
    float* __restrict__ hsumP, float* __restrict__ hsumN)
{
    int gt = blockIdx.x * 256 + threadIdx.x;
    int w = gt >> 6, lane = gt & 63;
    if (w >= NN) return;
    int es = lane >> 4, c4 = (lane & 15) << 2;
    int beg = row_start[w], end = row_start[w + 1];

    float p0 = 0.f, p1 = 0.f, p2 = 0.f, p3 = 0.f;
    float n0 = 0.f, n1 = 0.f, n2 = 0.f, n3 = 0.f;
    int i = beg + es;
    int s = (i < end) ? sorted[i].x : 0;
#pragma unroll 1
    for (; i < end; i += 4) {
        int inext = i + 4;
        int sn = (inext < end) ? sorted[inext].x : 0;
        float4 vP = *(const float4*)(hP + (size_t)s * D + c4);
        float4 vN = *(const float4*)(hN + (size_t)s * D + c4);
        p0 += vP.x; p1 += vP.y; p2 += vP.z; p3 += vP.w;
        n0 += vN.x; n1 += vN.y; n2 += vN.z; n3 += vN.w;
        s = sn;
    }
#pragma unroll
    for (int off = 16; off <= 32; off <<= 1) {
        p0 += __shfl_xor(p0, off, 64); p1 += __shfl_xor(p1, off, 64);
        p2 += __shfl_xor(p2, off, 64); p3 += __shfl_xor(p3, off, 64);
        n0 += __shfl_xor(n0, off, 64); n1 += __shfl_xor(n1, off, 64);
        n2 += __shfl_xor(n2, off, 64); n3 += __shfl_xor(n3, off, 64);
    }
    if (lane < 16) {
        *(float4*)(hsumP + (size_t)w * D + c4) = make_float4(p0, p1, p2, p3);
        *(float4*)(hsumN + (size_t)w * D + c4) = make_float4(n0, n1, n2, n3);
    }
}

// ================= global-operand SAGE layer kernels =================
// R7 restructure: A operands read straight from global (16-lane groups share
// the same address -> 4-line broadcast loads, L1/L2 served); B operands read
// from pre-transposed weights Wt[k][j] (256B contiguous wave reads, 32KB-hot).
// No weight staging, no A staging, no LDS tiles except the 17KB msg exchange.
// Barriers: 14 -> 4 per block (l1loss). LDS bank conflicts: gone by design.

__device__ __forceinline__ void gemm_gg(
    float acc[4][4], const float* const* Ap, const float* __restrict__ Bt)
{
    // acc[i][j] += sum_k A_i[k] * Bt[k*64 + j4];  Ap[i] = row base (clamped)
#pragma unroll 2
    for (int k0 = 0; k0 < 64; k0 += 4) {
        float a[4][4];
        float4 bv[4];
#pragma unroll
        for (int i = 0; i < 4; ++i)
            *(float4*)&a[i][0] = *(const float4*)(Ap[i] + k0);
#pragma unroll
        for (int kk = 0; kk < 4; ++kk)
            bv[kk] = *(const float4*)(Bt + (k0 + kk) * 64);
#pragma unroll
        for (int kk = 0; kk < 4; ++kk)
#pragma unroll
            for (int i = 0; i < 4; ++i) {
                acc[i][0] += a[i][kk] * bv[kk].x;
                acc[i][1] += a[i][kk] * bv[kk].y;
                acc[i][2] += a[i][kk] * bv[kk].z;
                acc[i][3] += a[i][kk] * bv[kk].w;
            }
    }
}

__device__ __forceinline__ void gemm_lg(
    float acc[4][4], const float (*As)[68], int ty, const float* __restrict__ Bt)
{
    // A from the LDS msg-exchange buffer (4 distinct rows x 16-lane broadcast,
    // banks 4*ty apart -> conflict-free), B from global Wt.
#pragma unroll 2
    for (int k0 = 0; k0 < 64; k0 += 4) {
        float a[4][4];
        float4 bv[4];
#pragma unroll
        for (int i = 0; i < 4; ++i)
            *(float4*)&a[i][0] = *(const float4*)&As[ty + 16 * i][k0];
#pragma unroll
        for (int kk = 0; kk < 4; ++kk)
            bv[kk] = *(const float4*)(Bt + (k0 + kk) * 64);
#pragma unroll
        for (int kk = 0; kk < 4; ++kk)
#pragma unroll
            for (int i = 0; i < 4; ++i) {
                acc[i][0] += a[i][kk] * bv[kk].x;
                acc[i][1] += a[i][kk] * bv[kk].y;
                acc[i][2] += a[i][kk] * bv[kk].z;
                acc[i][3] += a[i][kk] * bv[kk].w;
            }
    }
}

// Layer 0, both encodes. Hsum-half and Hprev-half shared between P/N.
__global__ __launch_bounds__(256, 4) void fused3_l0(
    const float* __restrict__ Hsum, const float* __restrict__ EsumP,
    const float* __restrict__ EsumN, const float* __restrict__ Hprev,
    const int* __restrict__ counts,
    const float* __restrict__ WtM, const float* __restrict__ bmsg,
    const float* __restrict__ WtA, const float* __restrict__ bap,
    float* __restrict__ HoutP, float* __restrict__ HoutN)
{
    __shared__ __align__(16) float As[64][68];    // msg exchange only, 17.4 KB
    int tid = threadIdx.x;
    int block0 = blockIdx.x * 64;
    int tx = tid & 15, ty = tid >> 4;
    int tx4 = tx << 2;

    size_t off[4];
    float cnt[4], inv[4];
#pragma unroll
    for (int i = 0; i < 4; ++i) {
        int gn = block0 + ty + 16 * i;
        int rc = (gn < NN) ? gn : (NN - 1);            // clamp OOB row loads
        off[i] = (size_t)rc * D;
        cnt[i] = (gn < NN) ? (float)counts[gn] : 0.f;
        inv[i] = 1.0f / fmaxf(cnt[i], 1.0f);
    }
    float bm[4], ba[4];
#pragma unroll
    for (int j = 0; j < 4; ++j) { bm[j] = bmsg[tx4 + j]; ba[j] = bap[tx4 + j]; }

    const float* BtM = WtM + tx4;        // Bt + k*64 = Wt[k][tx4]
    const float* BtA = WtA + tx4;
    const float* Ap[4];

    // ---- msg: shared Hsum half ----
    float accb[4][4] = {};
#pragma unroll
    for (int i = 0; i < 4; ++i) Ap[i] = Hsum + off[i];
    gemm_gg(accb, Ap, BtM);

    // ---- msg P: EsumP half ----
    float msgP[4][4];
#pragma unroll
    for (int i = 0; i < 4; ++i)
#pragma unroll
        for (int j = 0; j < 4; ++j) msgP[i][j] = accb[i][j];
#pragma unroll
    for (int i = 0; i < 4; ++i) Ap[i] = EsumP + off[i];
    gemm_gg(msgP, Ap, BtM + 64 * 64);
#pragma unroll
    for (int i = 0; i < 4; ++i)
#pragma unroll
        for (int j = 0; j < 4; ++j) msgP[i][j] = (msgP[i][j] + cnt[i] * bm[j]) * inv[i];
#pragma unroll
    for (int i = 0; i < 4; ++i)
        *(float4*)&As[ty + 16 * i][tx4] = make_float4(msgP[i][0], msgP[i][1], msgP[i][2], msgP[i][3]);

    // ---- apply: shared Hprev half (overlaps with As store visibility) ----
    float acc2b[4][4] = {};
#pragma unroll
    for (int i = 0; i < 4; ++i) Ap[i] = Hprev + off[i];
    gemm_gg(acc2b, Ap, BtA);

    __syncthreads();
    float acc2[4][4];
#pragma unroll
    for (int i = 0; i < 4; ++i)
#pragma unroll
        for (int j = 0; j < 4; ++j) acc2[i][j] = acc2b[i][j];
    gemm_lg(acc2, As, ty, BtA + 64 * 64);
#pragma unroll
    for (int i = 0; i < 4; ++i) {
        int gn = block0 + ty + 16 * i;
        if (gn >= NN) continue;
#pragma unroll
        for (int j = 0; j < 4; ++j)
            HoutP[(size_t)gn * D + tx4 + j] = fmaxf(acc2[i][j] + ba[j], 0.f);
    }

    // ---- msg N: EsumN half (reuse accb in place) ----
#pragma unroll
    for (int i = 0; i < 4; ++i) Ap[i] = EsumN + off[i];
    gemm_gg(accb, Ap, BtM + 64 * 64);
#pragma unroll
    for (int i = 0; i < 4; ++i)
#pragma unroll
        for (int j = 0; j < 4; ++j) accb[i][j] = (accb[i][j] + cnt[i] * bm[j]) * inv[i];

    __syncthreads();                      // all P-side As reads retired
#pragma unroll
    for (int i = 0; i < 4; ++i)
        *(float4*)&As[ty + 16 * i][tx4] = make_float4(accb[i][0], accb[i][1], accb[i][2], accb[i][3]);
    __syncthreads();
#pragma unroll
    for (int i = 0; i < 4; ++i)
#pragma unroll
        for (int j = 0; j < 4; ++j) acc2[i][j] = acc2b[i][j];
    gemm_lg(acc2, As, ty, BtA + 64 * 64);
#pragma unroll
    for (int i = 0; i < 4; ++i) {
        int gn = block0 + ty + 16 * i;
        if (gn >= NN) continue;
#pragma unroll
        for (int j = 0; j < 4; ++j)
            HoutN[(size_t)gn * D + tx4 + j] = fmaxf(acc2[i][j] + ba[j], 0.f);
    }
}

// Layer 1 + loss, both encodes.
__global__ __launch_bounds__(256, 4) void fused3_l1loss(
    const float* __restrict__ HsumP, const float* __restrict__ HsumN,
    const float* __restrict__ EsumP, const float* __restrict__ EsumN,
    const float* __restrict__ HprevP, const float* __restrict__ HprevN,
    const int* __restrict__ counts,
    const float* __restrict__ WtM, const float* __restrict__ bmsg,
    const float* __restrict__ WtA, const float* __restrict__ bap,
    float* __restrict__ loss_out)
{
    __shared__ __align__(16) float As[64][68];
    int tid = threadIdx.x;
    int block0 = blockIdx.x * 64;
    int tx = tid & 15, ty = tid >> 4;
    int tx4 = tx << 2;

    size_t off[4];
    float cnt[4], inv[4];
#pragma unroll
    for (int i = 0; i < 4; ++i) {
        int gn = block0 + ty + 16 * i;
        int rc = (gn < NN) ? gn : (NN - 1);
        off[i] = (size_t)rc * D;
        cnt[i] = (gn < NN) ? (float)counts[gn] : 0.f;
        inv[i] = 1.0f / fmaxf(cnt[i], 1.0f);
    }
    float bm[4], ba[4];
#pragma unroll
    for (int j = 0; j < 4; ++j) { bm[j] = bmsg[tx4 + j]; ba[j] = bap[tx4 + j]; }

    const float* BtM = WtM + tx4;
    const float* BtA = WtA + tx4;
    const float* Ap[4];

    float lsum = 0.f;
#pragma unroll 1
    for (int side = 0; side < 2; ++side) {
        const float* Hsum  = side ? HsumN  : HsumP;
        const float* Esum  = side ? EsumN  : EsumP;
        const float* Hprev = side ? HprevN : HprevP;

        // msg GEMM (K=128: Hsum half + Esum half)
        float acc[4][4] = {};
#pragma unroll
        for (int i = 0; i < 4; ++i) Ap[i] = Hsum + off[i];
        gemm_gg(acc, Ap, BtM);
#pragma unroll
        for (int i = 0; i < 4; ++i) Ap[i] = Esum + off[i];
        gemm_gg(acc, Ap, BtM + 64 * 64);
        float msg[4][4];
#pragma unroll
        for (int i = 0; i < 4; ++i)
#pragma unroll
            for (int j = 0; j < 4; ++j) msg[i][j] = (acc[i][j] + cnt[i] * bm[j]) * inv[i];

        // apply GEMM: Hprev half from global, msg half via LDS exchange
        float acc2[4][4] = {};
#pragma unroll
        for (int i = 0; i < 4; ++i) Ap[i] = Hprev + off[i];
        gemm_gg(acc2, Ap, BtA);

        __syncthreads();                  // previous side's As reads retired
#pragma unroll
        for (int i = 0; i < 4; ++i)
            *(float4*)&As[ty + 16 * i][tx4] = make_float4(msg[i][0], msg[i][1], msg[i][2], msg[i][3]);
        __syncthreads();
        gemm_lg(acc2, As, ty, BtA + 64 * 64);

#pragma unroll
        for (int i = 0; i < 4; ++i) {
            int gn = block0 + ty + 16 * i;
            if (gn >= NN) continue;
#pragma unroll
            for (int j = 0; j < 4; ++j) {
                float x = fmaxf(acc2[i][j] + ba[j], 0.f);
                float l = log1pf(expf(-x));      // pos: softplus(-x)
                if (side) l += x;                // neg: softplus(x)
                lsum += l;
            }
        }
    }
#pragma unroll
    for (int off2 = 32; off2; off2 >>= 1) lsum += __shfl_down(lsum, off2, 64);
    if ((tid & 63) == 0)
        unsafeAtomicAdd(loss_out, lsum * (1.0f / 6400000.0f)); // / (N*64)
}

// ================= launch =================
extern "C" void kernel_launch(void* const* d_in, const int* in_sizes, int n_in,
                              void* d_out, int out_size, void* d_ws, size_t ws_size,
                              hipStream_t stream) {
    (void)in_sizes; (void)n_in; (void)out_size; (void)ws_size;
    const float* nfeats = (const float*)d_in[0];
    const float* efeats = (const float*)d_in[1];
    const int*   src    = (const int*)d_in[2];
    const int*   dst    = (const int*)d_in[3];
    const int*   perm   = (const int*)d_in[4];
    const float* Wmsg0  = (const float*)d_in[5];
    const float* bmsg0  = (const float*)d_in[6];
    const float* Wap0   = (const float*)d_in[7];
    const float* bap0   = (const float*)d_in[8];
    const float* Wmsg1  = (const float*)d_in[9];
    const float* bmsg1  = (const float*)d_in[10];
    const float* Wap1   = (const float*)d_in[11];
    const float* bap1   = (const float*)d_in[12];
    float* out = (float*)d_out;

    // ---- workspace layout (16B-aligned chunks; d_ws is ~1 GB) ----
    const size_t NV = (size_t)NN * D;
    char* p = (char*)d_ws;
    int4* sorted   = (int4*)p;               p += (size_t)NE * 16;   // 16 MB
    int*  rank     = (int*)p;                p += (size_t)NE * 4;    // 4 MB
    int*  counts   = (int*)p;                p += ((NN + 15) & ~15) * 4;
    int*  rowst    = (int*)p;                p += ((NN + 16) & ~15) * 4;
    int*  bsum     = (int*)p;                p += 512 * 4;
    int*  boff     = (int*)p;                p += 512 * 4;
    float* efsP    = (float*)p;              p += NV * 4;            // 25.6 MB each
    float* efsN    = (float*)p;              p += NV * 4;
    float* hsum0   = (float*)p;              p += NV * 4;
    float* h1P     = (float*)p;              p += NV * 4;
    float* h1N     = (float*)p;              p += NV * 4;
    float* hsum1P  = (float*)p;              p += NV * 4;
    float* hsum1N  = (float*)p;              p += NV * 4;
    float* wtM0    = (float*)p;              p += 8192 * 4;          // 32 KB each
    float* wtA0    = (float*)p;              p += 8192 * 4;
    float* wtM1    = (float*)p;              p += 8192 * 4;
    float* wtA1    = (float*)p;              p += 8192 * 4;

    const int EGb = (NE + 255) / 256;        // 3907
    const int PGb = ((size_t)NN * 64 + 255) / 256;  // 25000
    const int NG  = (NN + 63) / 64;          // 1563

    hipMemsetAsync(counts, 0, (size_t)NN * 4, stream);
    hipMemsetAsync(d_out, 0, 4, stream);

    // ---- weight transpose (tiny, once) ----
    k_wt4<<<128, 256, 0, stream>>>(Wmsg0, Wap0, Wmsg1, Wap1, wtM0, wtA0, wtM1, wtA1);

    // ---- CSR build ----
    k_hist<<<EGb, 256, 0, stream>>>(dst, counts, rank);
    k_scan1<<<NB_SCAN, 256, 0, stream>>>(counts, rowst, bsum);
    k_scan2<<<1, 512, 0, stream>>>(bsum, boff, rowst);
    k_scan3<<<NB_SCAN, 256, 0, stream>>>(rowst, boff);
    k_scatter<<<EGb, 256, 0, stream>>>(dst, src, perm, rank, rowst, sorted);

    // ---- all first-layer segment sums in one pass ----
    pull_pass1<<<PGb, 256, 0, stream>>>(sorted, rowst, nfeats, efeats, hsum0, efsP, efsN);

    // ---- layer 0 merged (shared Hsum + shared Hprev halves) ----
    fused3_l0<<<NG, 256, 0, stream>>>(hsum0, efsP, efsN, nfeats, counts,
                                      wtM0, bmsg0, wtA0, bap0, h1P, h1N);

    // ---- one dual pull for both encodes' h1 ----
    pull_h2<<<PGb, 256, 0, stream>>>(sorted, rowst, h1P, h1N, hsum1P, hsum1N);

    // ---- layer 1 + both losses in one dispatch ----
    fused3_l1loss<<<NG, 256, 0, stream>>>(hsum1P, hsum1N, efsP, efsN, h1P, h1N,
                                          counts, wtM1, bmsg1, wtA1, bap1, out);
}

// Round 2
// 870.164 us; speedup vs baseline: 1.1659x; 1.1659x over previous
//
#include <hip/hip_runtime.h>
#include <math.h>

#define NN 100000
#define NE 1000000
#define D  64
#define NB_SCAN 391   // ceil(NN/256)

// ================= CSR build (counting sort by dst) =================

__global__ __launch_bounds__(256) void k_hist(
    const int* __restrict__ dst, int* __restrict__ counts, int* __restrict__ rank)
{
    int e = blockIdx.x * 256 + threadIdx.x;
    if (e >= NE) return;
    rank[e] = atomicAdd(&counts[dst[e]], 1);
}

__global__ __launch_bounds__(256) void k_scan1(
    const int* __restrict__ counts, int* __restrict__ row_start, int* __restrict__ bsum)
{
    __shared__ int s[256];
    int t = threadIdx.x;
    int i = blockIdx.x * 256 + t;
    int v = (i < NN) ? counts[i] : 0;
    s[t] = v; __syncthreads();
#pragma unroll
    for (int off = 1; off < 256; off <<= 1) {
        int add = (t >= off) ? s[t - off] : 0;
        __syncthreads();
        s[t] += add;
        __syncthreads();
    }
    if (i < NN) row_start[i] = s[t] - v;       // local exclusive
    if (t == 255) bsum[blockIdx.x] = s[255];   // block total
}

__global__ __launch_bounds__(512) void k_scan2(
    const int* __restrict__ bsum, int* __restrict__ boff, int* __restrict__ row_start)
{
    __shared__ int s[512];
    int t = threadIdx.x;
    int v = (t < NB_SCAN) ? bsum[t] : 0;
    s[t] = v; __syncthreads();
#pragma unroll
    for (int off = 1; off < 512; off <<= 1) {
        int add = (t >= off) ? s[t - off] : 0;
        __syncthreads();
        s[t] += add;
        __syncthreads();
    }
    if (t < NB_SCAN) boff[t] = s[t] - v;       // exclusive block offsets
    if (t == 0) row_start[NN] = NE;
}

__global__ __launch_bounds__(256) void k_scan3(
    int* __restrict__ row_start, const int* __restrict__ boff)
{
    int i = blockIdx.x * 256 + threadIdx.x;
    if (i < NN) row_start[i] += boff[i >> 8];
}

__global__ __launch_bounds__(256) void k_scatter(
    const int* __restrict__ dst, const int* __restrict__ src,
    const int* __restrict__ perm, const int* __restrict__ rank,
    const int* __restrict__ row_start, int4* __restrict__ sorted)
{
    int e = blockIdx.x * 256 + threadIdx.x;
    if (e >= NE) return;
    int pos = row_start[dst[e]] + rank[e];
    sorted[pos] = make_int4(src[e], e, perm[e], 0);   // single 16B line-local write
}

// one-time weight transpose: W[64][128] (torch [out][in]) -> Wt[128][64]
// so B staging in the GEMM kernels is a pure contiguous float4 copy.
__global__ __launch_bounds__(256) void k_wt4(
    const float* __restrict__ W0, const float* __restrict__ W1,
    const float* __restrict__ W2, const float* __restrict__ W3,
    float* __restrict__ T0, float* __restrict__ T1,
    float* __restrict__ T2, float* __restrict__ T3)
{
    int t = blockIdx.x * 256 + threadIdx.x;   // 4 * 8192 elements
    int m = t >> 13, idx = t & 8191;
    const float* W = (m == 0) ? W0 : (m == 1) ? W1 : (m == 2) ? W2 : W3;
    float*       T = (m == 0) ? T0 : (m == 1) ? T1 : (m == 2) ? T2 : T3;
    int j = idx >> 7, k = idx & 127;
    T[k * 64 + j] = W[idx];
}

// ================= pull-based segment sums (no atomics) =================

__global__ __launch_bounds__(256) void pull_pass1(
    const int4* __restrict__ sorted, const int* __restrict__ row_start,
    const float* __restrict__ nfeats, const float* __restrict__ efeats,
    float* __restrict__ hsum0, float* __restrict__ efsP, float* __restrict__ efsN)
{
    int gt = blockIdx.x * 256 + threadIdx.x;
    int w = gt >> 6, lane = gt & 63;
    if (w >= NN) return;
    int es = lane >> 4, c4 = (lane & 15) << 2;
    int beg = row_start[w], end = row_start[w + 1];

    float an0 = 0.f, an1 = 0.f, an2 = 0.f, an3 = 0.f;
    float ap0 = 0.f, ap1 = 0.f, ap2 = 0.f, ap3 = 0.f;
    float ag0 = 0.f, ag1 = 0.f, ag2 = 0.f, ag3 = 0.f;
    int i = beg + es;
    int4 q = (i < end) ? sorted[i] : make_int4(0, 0, 0, 0);
#pragma unroll 1
    for (; i < end; i += 4) {
        int inext = i + 4;
        int4 qn = (inext < end) ? sorted[inext] : make_int4(0, 0, 0, 0);
        float4 n  = *(const float4*)(nfeats + (size_t)q.x * D + c4);
        float4 ep = *(const float4*)(efeats + (size_t)q.y * D + c4);
        float4 en = *(const float4*)(efeats + (size_t)q.z * D + c4);
        an0 += n.x;  an1 += n.y;  an2 += n.z;  an3 += n.w;
        ap0 += ep.x; ap1 += ep.y; ap2 += ep.z; ap3 += ep.w;
        ag0 += en.x; ag1 += en.y; ag2 += en.z; ag3 += en.w;
        q = qn;
    }
#pragma unroll
    for (int off = 16; off <= 32; off <<= 1) {
        an0 += __shfl_xor(an0, off, 64); an1 += __shfl_xor(an1, off, 64);
        an2 += __shfl_xor(an2, off, 64); an3 += __shfl_xor(an3, off, 64);
        ap0 += __shfl_xor(ap0, off, 64); ap1 += __shfl_xor(ap1, off, 64);
        ap2 += __shfl_xor(ap2, off, 64); ap3 += __shfl_xor(ap3, off, 64);
        ag0 += __shfl_xor(ag0, off, 64); ag1 += __shfl_xor(ag1, off, 64);
        ag2 += __shfl_xor(ag2, off, 64); ag3 += __shfl_xor(ag3, off, 64);
    }
    if (lane < 16) {
        *(float4*)(hsum0 + (size_t)w * D + c4) = make_float4(an0, an1, an2, an3);
        *(float4*)(efsP  + (size_t)w * D + c4) = make_float4(ap0, ap1, ap2, ap3);
        *(float4*)(efsN  + (size_t)w * D + c4) = make_float4(ag0, ag1, ag2, ag3);
    }
}

__global__ __launch_bounds__(256) void pull_h2(
    const int4* __restrict__ sorted, const int* __restrict__ row_start,
    const float* __restrict__ hP, const float* __restrict__ hN,
    float* __restrict__ hsumP, float* __restrict__ hsumN)
{
    int gt = blockIdx.x * 256 + threadIdx.x;
    int w = gt >> 6, lane = gt & 63;
    if (w >= NN) return;
    int es = lane >> 4, c4 = (lane & 15) << 2;
    int beg = row_start[w], end = row_start[w + 1];

    float p0 = 0.f, p1 = 0.f, p2 = 0.f, p3 = 0.f;
    float n0 = 0.f, n1 = 0.f, n2 = 0.f, n3 = 0.f;
    int i = beg + es;
    int s = (i < end) ? sorted[i].x : 0;
#pragma unroll 1
    for (; i < end; i += 4) {
        int inext = i + 4;
        int sn = (inext < end) ? sorted[inext].x : 0;
        float4 vP = *(const float4*)(hP + (size_t)s * D + c4);
        float4 vN = *(const float4*)(hN + (size_t)s * D + c4);
        p0 += vP.x; p1 += vP.y; p2 += vP.z; p3 += vP.w;
        n0 += vN.x; n1 += vN.y; n2 += vN.z; n3 += vN.w;
        s = sn;
    }
#pragma unroll
    for (int off = 16; off <= 32; off <<= 1) {
        p0 += __shfl_xor(p0, off, 64); p1 += __shfl_xor(p1, off, 64);
        p2 += __shfl_xor(p2, off, 64); p3 += __shfl_xor(p3, off, 64);
        n0 += __shfl_xor(n0, off, 64); n1 += __shfl_xor(n1, off, 64);
        n2 += __shfl_xor(n2, off, 64); n3 += __shfl_xor(n3, off, 64);
    }
    if (lane < 16) {
        *(float4*)(hsumP + (size_t)w * D + c4) = make_float4(p0, p1, p2, p3);
        *(float4*)(hsumN + (size_t)w * D + c4) = make_float4(n0, n1, n2, n3);
    }
}

// ================= LDS-staged SAGE layer kernels (fused4) =================
// R2: back to the fused2 LDS structure (R1's global-operand version was
// VMEM-latency-bound: VALUBusy 54->38, dur 204->261). Fixes vs fused2:
//  - B staged from PRE-TRANSPOSED Wt via contiguous float4 copy: kills the
//    4.8M bank-conflict cycles (fused2's scalar stride-68 column writes)
//    and the 32-iteration scalar weight loads.
//  - B staged in 64-row HALVES (Bs[64][68], 17KB): same staged bytes, but
//    LDS/block 52->35KB -> 4 blocks/CU instead of 3 (16 vs 12 waves).

__device__ __forceinline__ void gemm_h(
    float acc[4][4], const float (*As)[68], const float (*Bs)[68],
    int ty, int tx4)
{
#pragma unroll 1
    for (int k0 = 0; k0 < 64; k0 += 4) {
        float a[4][4];
        float4 bv[4];
#pragma unroll
        for (int i = 0; i < 4; ++i)
            *(float4*)&a[i][0] = *(const float4*)&As[ty + 16 * i][k0];
#pragma unroll
        for (int kk = 0; kk < 4; ++kk)
            bv[kk] = *(const float4*)&Bs[k0 + kk][tx4];
#pragma unroll
        for (int kk = 0; kk < 4; ++kk)
#pragma unroll
            for (int i = 0; i < 4; ++i) {
                acc[i][0] += a[i][kk] * bv[kk].x;
                acc[i][1] += a[i][kk] * bv[kk].y;
                acc[i][2] += a[i][kk] * bv[kk].z;
                acc[i][3] += a[i][kk] * bv[kk].w;
            }
    }
}

#define STAGE_A(SRC) { \
    _Pragma("unroll") \
    for (int g = 0; g < 4; ++g) { \
        int idx = g * 256 + tid; \
        int node = idx >> 4, c = (idx & 15) << 2; \
        int gn = block0 + node; \
        float4 v = make_float4(0.f, 0.f, 0.f, 0.f); \
        if (gn < NN) v = *(const float4*)((SRC) + (size_t)gn * D + c); \
        *(float4*)&As[node][c] = v; } }

// contiguous float4 copy of one 64-row half of Wt[128][64] into Bs[64][68]
#define STAGE_BH(WT, HALF) { \
    _Pragma("unroll") \
    for (int g = 0; g < 4; ++g) { \
        int m = g * 256 + tid; \
        *(float4*)&Bs[m >> 4][(m & 15) << 2] = \
            *(const float4*)((WT) + (HALF) * 4096 + m * 4); } }

#define STORE_MSG(M) { \
    _Pragma("unroll") \
    for (int i = 0; i < 4; ++i) \
        *(float4*)&As[ty + 16 * i][tx4] = make_float4((M)[i][0], (M)[i][1], (M)[i][2], (M)[i][3]); }

// Layer 0, both encodes. Hsum-half and Hprev-half shared between P/N.
__global__ __launch_bounds__(256, 4) void fused4_l0(
    const float* __restrict__ Hsum, const float* __restrict__ EsumP,
    const float* __restrict__ EsumN, const float* __restrict__ Hprev,
    const int* __restrict__ counts,
    const float* __restrict__ WtM, const float* __restrict__ bmsg,
    const float* __restrict__ WtA, const float* __restrict__ bap,
    float* __restrict__ HoutP, float* __restrict__ HoutN)
{
    __shared__ __align__(16) float As[64][68];    // 17.4 KB
    __shared__ __align__(16) float Bs[64][68];    // 17.4 KB
    int tid = threadIdx.x;
    int block0 = blockIdx.x * 64;
    int tx = tid & 15, ty = tid >> 4;
    int tx4 = tx << 2;

    float cnt[4], inv[4];
#pragma unroll
    for (int i = 0; i < 4; ++i) {
        int gn = block0 + ty + 16 * i;
        cnt[i] = (gn < NN) ? (float)counts[gn] : 0.f;
        inv[i] = 1.0f / fmaxf(cnt[i], 1.0f);
    }
    float bm[4], ba[4];
#pragma unroll
    for (int j = 0; j < 4; ++j) { bm[j] = bmsg[tx4 + j]; ba[j] = bap[tx4 + j]; }

    // ---- P1: shared Hsum · WmT[0:64) ----
    STAGE_BH(WtM, 0);
    STAGE_A(Hsum);
    __syncthreads();
    float accb[4][4] = {};
    gemm_h(accb, As, Bs, ty, tx4);

    // ---- P2: msgP = accb + EsumP · WmT[64:128) ----
    __syncthreads();
    STAGE_BH(WtM, 1);
    STAGE_A(EsumP);
    __syncthreads();
    float msgP[4][4];
#pragma unroll
    for (int i = 0; i < 4; ++i)
#pragma unroll
        for (int j = 0; j < 4; ++j) msgP[i][j] = accb[i][j];
    gemm_h(msgP, As, Bs, ty, tx4);
#pragma unroll
    for (int i = 0; i < 4; ++i)
#pragma unroll
        for (int j = 0; j < 4; ++j) msgP[i][j] = (msgP[i][j] + cnt[i] * bm[j]) * inv[i];

    // ---- P3: msgN (Bs unchanged, only As restaged) ----
    __syncthreads();
    STAGE_A(EsumN);
    __syncthreads();
    gemm_h(accb, As, Bs, ty, tx4);        // accb -> raw msgN
#pragma unroll
    for (int i = 0; i < 4; ++i)
#pragma unroll
        for (int j = 0; j < 4; ++j) accb[i][j] = (accb[i][j] + cnt[i] * bm[j]) * inv[i];

    // ---- P4: shared Hprev · WaT[0:64) ----
    __syncthreads();
    STAGE_BH(WtA, 0);
    STAGE_A(Hprev);
    __syncthreads();
    float acc2b[4][4] = {};
    gemm_h(acc2b, As, Bs, ty, tx4);

    // ---- P5: HoutP = relu(acc2b + msgP · WaT[64:128) + ba) ----
    __syncthreads();
    STAGE_BH(WtA, 1);
    STORE_MSG(msgP);
    __syncthreads();
    float acc2[4][4];
#pragma unroll
    for (int i = 0; i < 4; ++i)
#pragma unroll
        for (int j = 0; j < 4; ++j) acc2[i][j] = acc2b[i][j];
    gemm_h(acc2, As, Bs, ty, tx4);
#pragma unroll
    for (int i = 0; i < 4; ++i) {
        int gn = block0 + ty + 16 * i;
        if (gn >= NN) continue;
#pragma unroll
        for (int j = 0; j < 4; ++j)
            HoutP[(size_t)gn * D + tx4 + j] = fmaxf(acc2[i][j] + ba[j], 0.f);
    }

    // ---- P6: HoutN (Bs unchanged, As <- msgN) ----
    __syncthreads();
    STORE_MSG(accb);
    __syncthreads();
#pragma unroll
    for (int i = 0; i < 4; ++i)
#pragma unroll
        for (int j = 0; j < 4; ++j) acc2[i][j] = acc2b[i][j];
    gemm_h(acc2, As, Bs, ty, tx4);
#pragma unroll
    for (int i = 0; i < 4; ++i) {
        int gn = block0 + ty + 16 * i;
        if (gn >= NN) continue;
#pragma unroll
        for (int j = 0; j < 4; ++j)
            HoutN[(size_t)gn * D + tx4 + j] = fmaxf(acc2[i][j] + ba[j], 0.f);
    }
}

// Layer 1 + loss, both encodes. Hsum/Esum/Hprev all differ per side here;
// per-side loop with half-B restaging.
__global__ __launch_bounds__(256, 4) void fused4_l1loss(
    const float* __restrict__ HsumP, const float* __restrict__ HsumN,
    const float* __restrict__ EsumP, const float* __restrict__ EsumN,
    const float* __restrict__ HprevP, const float* __restrict__ HprevN,
    const int* __restrict__ counts,
    const float* __restrict__ WtM, const float* __restrict__ bmsg,
    const float* __restrict__ WtA, const float* __restrict__ bap,
    float* __restrict__ loss_out)
{
    __shared__ __align__(16) float As[64][68];
    __shared__ __align__(16) float Bs[64][68];
    int tid = threadIdx.x;
    int block0 = blockIdx.x * 64;
    int tx = tid & 15, ty = tid >> 4;
    int tx4 = tx << 2;

    float cnt[4], inv[4];
#pragma unroll
    for (int i = 0; i < 4; ++i) {
        int gn = block0 + ty + 16 * i;
        cnt[i] = (gn < NN) ? (float)counts[gn] : 0.f;
        inv[i] = 1.0f / fmaxf(cnt[i], 1.0f);
    }
    float bm[4], ba[4];
#pragma unroll
    for (int j = 0; j < 4; ++j) { bm[j] = bmsg[tx4 + j]; ba[j] = bap[tx4 + j]; }

    float lsum = 0.f;
#pragma unroll 1
    for (int side = 0; side < 2; ++side) {
        const float* Hsum  = side ? HsumN  : HsumP;
        const float* Esum  = side ? EsumN  : EsumP;
        const float* Hprev = side ? HprevN : HprevP;

        // msg GEMM: Hsum · WmT[0:64) + Esum · WmT[64:128)
        __syncthreads();                  // prior side's LDS reads retired
        STAGE_BH(WtM, 0);
        STAGE_A(Hsum);
        __syncthreads();
        float acc[4][4] = {};
        gemm_h(acc, As, Bs, ty, tx4);

        __syncthreads();
        STAGE_BH(WtM, 1);
        STAGE_A(Esum);
        __syncthreads();
        gemm_h(acc, As, Bs, ty, tx4);
        float msg[4][4];
#pragma unroll
        for (int i = 0; i < 4; ++i)
#pragma unroll
            for (int j = 0; j < 4; ++j) msg[i][j] = (acc[i][j] + cnt[i] * bm[j]) * inv[i];

        // apply GEMM: Hprev · WaT[0:64) + msg · WaT[64:128)
        __syncthreads();
        STAGE_BH(WtA, 0);
        STAGE_A(Hprev);
        __syncthreads();
        float acc2[4][4] = {};
        gemm_h(acc2, As, Bs, ty, tx4);

        __syncthreads();
        STAGE_BH(WtA, 1);
        STORE_MSG(msg);
        __syncthreads();
        gemm_h(acc2, As, Bs, ty, tx4);

#pragma unroll
        for (int i = 0; i < 4; ++i) {
            int gn = block0 + ty + 16 * i;
            if (gn >= NN) continue;
#pragma unroll
            for (int j = 0; j < 4; ++j) {
                float x = fmaxf(acc2[i][j] + ba[j], 0.f);
                float l = log1pf(expf(-x));      // pos: softplus(-x)
                if (side) l += x;                // neg: softplus(x)
                lsum += l;
            }
        }
    }
#pragma unroll
    for (int off2 = 32; off2; off2 >>= 1) lsum += __shfl_down(lsum, off2, 64);
    if ((tid & 63) == 0)
        unsafeAtomicAdd(loss_out, lsum * (1.0f / 6400000.0f)); // / (N*64)
}

// ================= launch =================
extern "C" void kernel_launch(void* const* d_in, const int* in_sizes, int n_in,
                              void* d_out, int out_size, void* d_ws, size_t ws_size,
                              hipStream_t stream) {
    (void)in_sizes; (void)n_in; (void)out_size; (void)ws_size;
    const float* nfeats = (const float*)d_in[0];
    const float* efeats = (const float*)d_in[1];
    const int*   src    = (const int*)d_in[2];
    const int*   dst    = (const int*)d_in[3];
    const int*   perm   = (const int*)d_in[4];
    const float* Wmsg0  = (const float*)d_in[5];
    const float* bmsg0  = (const float*)d_in[6];
    const float* Wap0   = (const float*)d_in[7];
    const float* bap0   = (const float*)d_in[8];
    const float* Wmsg1  = (const float*)d_in[9];
    const float* bmsg1  = (const float*)d_in[10];
    const float* Wap1   = (const float*)d_in[11];
    const float* bap1   = (const float*)d_in[12];
    float* out = (float*)d_out;

    // ---- workspace layout (16B-aligned chunks; d_ws is ~1 GB) ----
    const size_t NV = (size_t)NN * D;
    char* p = (char*)d_ws;
    int4* sorted   = (int4*)p;               p += (size_t)NE * 16;   // 16 MB
    int*  rank     = (int*)p;                p += (size_t)NE * 4;    // 4 MB
    int*  counts   = (int*)p;                p += ((NN + 15) & ~15) * 4;
    int*  rowst    = (int*)p;                p += ((NN + 16) & ~15) * 4;
    int*  bsum     = (int*)p;                p += 512 * 4;
    int*  boff     = (int*)p;                p += 512 * 4;
    float* efsP    = (float*)p;              p += NV * 4;            // 25.6 MB each
    float* efsN    = (float*)p;              p += NV * 4;
    float* hsum0   = (float*)p;              p += NV * 4;
    float* h1P     = (float*)p;              p += NV * 4;
    float* h1N     = (float*)p;              p += NV * 4;
    float* hsum1P  = (float*)p;              p += NV * 4;
    float* hsum1N  = (float*)p;              p += NV * 4;
    float* wtM0    = (float*)p;              p += 8192 * 4;          // 32 KB each
    float* wtA0    = (float*)p;              p += 8192 * 4;
    float* wtM1    = (float*)p;              p += 8192 * 4;
    float* wtA1    = (float*)p;              p += 8192 * 4;

    const int EGb = (NE + 255) / 256;        // 3907
    const int PGb = ((size_t)NN * 64 + 255) / 256;  // 25000
    const int NG  = (NN + 63) / 64;          // 1563

    hipMemsetAsync(counts, 0, (size_t)NN * 4, stream);
    hipMemsetAsync(d_out, 0, 4, stream);

    // ---- weight transpose (tiny, once) ----
    k_wt4<<<128, 256, 0, stream>>>(Wmsg0, Wap0, Wmsg1, Wap1, wtM0, wtA0, wtM1, wtA1);

    // ---- CSR build ----
    k_hist<<<EGb, 256, 0, stream>>>(dst, counts, rank);
    k_scan1<<<NB_SCAN, 256, 0, stream>>>(counts, rowst, bsum);
    k_scan2<<<1, 512, 0, stream>>>(bsum, boff, rowst);
    k_scan3<<<NB_SCAN, 256, 0, stream>>>(rowst, boff);
    k_scatter<<<EGb, 256, 0, stream>>>(dst, src, perm, rank, rowst, sorted);

    // ---- all first-layer segment sums in one pass ----
    pull_pass1<<<PGb, 256, 0, stream>>>(sorted, rowst, nfeats, efeats, hsum0, efsP, efsN);

    // ---- layer 0 merged (shared Hsum + shared Hprev halves) ----
    fused4_l0<<<NG, 256, 0, stream>>>(hsum0, efsP, efsN, nfeats, counts,
                                      wtM0, bmsg0, wtA0, bap0, h1P, h1N);

    // ---- one dual pull for both encodes' h1 ----
    pull_h2<<<PGb, 256, 0, stream>>>(sorted, rowst, h1P, h1N, hsum1P, hsum1N);

    // ---- layer 1 + both losses in one dispatch ----
    fused4_l1loss<<<NG, 256, 0, stream>>>(hsum1P, hsum1N, efsP, efsN, h1P, h1N,
                                          counts, wtM1, bmsg1, wtA1, bap1, out);
}